// Round 5
// baseline (156.287 us; speedup 1.0000x reference)
//
#include <hip/hip_runtime.h>

typedef __bf16 v8bf __attribute__((ext_vector_type(8)));
typedef __bf16 v4bf __attribute__((ext_vector_type(4)));
typedef __bf16 v2bf __attribute__((ext_vector_type(2)));
typedef float  v4f  __attribute__((ext_vector_type(4)));

namespace {

constexpr int kB = 512, kM = 4096, kH = 8;

// ws layout (bytes)
constexpr size_t WS_QIN = 0;                                   // 512*4096 bf16 = 4 MB (tile-swizzled)
constexpr size_t WS_O   = (size_t)4 << 20;                     // 32768*512 bf16 = 32 MB (tile-swizzled)
constexpr size_t WS_WFC = WS_O + (size_t)32768 * 512 * 2;      // 32768 bf16 (B-tiles)
constexpr size_t WS_WQK = WS_WFC + 65536;                      // 8*4096 bf16 (B-tiles, per head)

// Tile swizzle: element (r, c) of a row-major [R x C] matrix lives at
//   tile = (r>>4)*(C/32) + (c>>5);  addr = tile*512 + (r&15)*32 + (c&31)

// ---------------- K0: Wfc cast + swizzle ----------------
__global__ __launch_bounds__(256) void k0_wfc(
    const float* __restrict__ Wfc, __bf16* __restrict__ wfc) {
  int j = blockIdx.x * 256 + threadIdx.x;   // 32768
  int o = j >> 9, f = j & 511;
  int dst = ((o >> 4) * 16 + (f >> 5)) * 512 + (o & 15) * 32 + (f & 31);
  wfc[dst] = (__bf16)Wfc[j];
}

// ---------------- K0b: Wqk[h] = Wq_h^T * Wk_h / 64, stored as B-tiles of Wqk^T ----------------
__global__ __launch_bounds__(256) void k0b_wqk(
    const float* __restrict__ Wq, const float* __restrict__ Wk,
    __bf16* __restrict__ wqk) {
  __shared__ float sq[2048], sk[2048];
  const int h = blockIdx.x, t = threadIdx.x;
#pragma unroll
  for (int j = 0; j < 8; ++j) {
    sq[t + j * 256] = Wq[h * 2048 + t + j * 256] * 0.015625f;
    sk[t + j * 256] = Wk[h * 2048 + t + j * 256];
  }
  __syncthreads();
  const int kp = t >> 2, kbase = (t & 3) * 16;   // k' = kp, k in [kbase, kbase+16)
  float wkr[32];
#pragma unroll
  for (int d = 0; d < 32; ++d) wkr[d] = sk[d * 64 + kp];
#pragma unroll
  for (int j = 0; j < 16; ++j) {
    int k = kbase + j;
    float acc = 0.f;
#pragma unroll
    for (int d = 0; d < 32; ++d) acc = fmaf(sq[d * 64 + k], wkr[d], acc);
    // Wqk^T[k'][k], B-tile swizzle
    int dst = h * 4096 + ((kp >> 4) * 2 + (k >> 5)) * 512 + (kp & 15) * 32 + (k & 31);
    wqk[dst] = (__bf16)acc;
  }
}

// ---------------- K1: LayerNorm -> bf16 qin (tile-swizzled) ----------------
__global__ __launch_bounds__(256) void k1_ln(
    const float* __restrict__ feat, const float* __restrict__ gamma,
    const float* __restrict__ beta, __bf16* __restrict__ qin) {
  __shared__ float red[4];
  const int b = blockIdx.x, t = threadIdx.x, lane = t & 63, wv = t >> 6;
  const float* frow = feat + (size_t)b * kM;
  float xs[16];
  float s = 0.f;
#pragma unroll
  for (int j = 0; j < 16; ++j) { float x = frow[t + j * 256]; xs[j] = x; s += x; }
#pragma unroll
  for (int o = 32; o > 0; o >>= 1) s += __shfl_xor(s, o);
  if (lane == 0) red[wv] = s;
  __syncthreads();
  const float mu = (red[0] + red[1] + red[2] + red[3]) * (1.f / kM);
  float v = 0.f;
#pragma unroll
  for (int j = 0; j < 16; ++j) { float d = xs[j] - mu; v += d * d; }
#pragma unroll
  for (int o = 32; o > 0; o >>= 1) v += __shfl_xor(v, o);
  __syncthreads();
  if (lane == 0) red[wv] = v;
  __syncthreads();
  const float var  = (red[0] + red[1] + red[2] + red[3]) * (1.f / kM);
  const float rstd = rsqrtf(var + 1e-5f);
#pragma unroll
  for (int j = 0; j < 16; ++j) {
    int m = t + j * 256;
    int n = m >> 6, k = m & 63;
    int dst = ((n >> 4) * 2 + (k >> 5)) * 512 + (n & 15) * 32 + (k & 31);
    qin[(size_t)b * kM + dst] = (__bf16)((xs[j] - mu) * rstd * gamma[m] + beta[m]);
  }
}

// ---------------- K2: per-(b,h) attention core (Wqk-fused) ----------------
// LDS 27,648 B -> 5 blocks/CU = 20 waves.
__global__ __launch_bounds__(256, 5) void k2_attn(
    const float* __restrict__ feat, const int* __restrict__ sidx,
    const __bf16* __restrict__ qin, const __bf16* __restrict__ wqk,
    const float* __restrict__ Wv1, const float* __restrict__ Wv2,
    __bf16* __restrict__ o_ws, float* __restrict__ out) {
  __shared__ __align__(16) __bf16 smem[13824];  // 27,648 B
  __bf16* s_kf = smem;          // 64x72: kf; after bD re-used for attn bf16 (wave-own rows)
  __bf16* s_x  = smem + 4608;   // region2: feat bf16 (4096) until bB, then tmp 64x72
  __bf16* s_vT = smem + 9216;   // 64x72: v^T [s][n]

  const int b = blockIdx.x, h = blockIdx.y;   // heads of one b -> same XCD (%8)
  const int t = threadIdx.x, w = t >> 6, lid = t & 63;
  const int quad = lid >> 4, l16 = lid & 15;

  const float*  frow  = feat + (size_t)b * kM;
  const int*    idxh  = sidx + h * kM;
  const __bf16* qin_b = qin + (size_t)b * kM;
  const __bf16* wqk_h = wqk + h * 4096;
  float* attn_out = out + (size_t)kB * kM + ((size_t)(b * kH + h)) * 4096;

  // ---- P0a: prefetch gather indices
  int idxr[16];
#pragma unroll
  for (int j = 0; j < 16; ++j) idxr[j] = idxh[t + j * 256];

  // ---- P0b: stage feature row bf16 into s_x (coalesced float4)
  {
    const float4* frow4 = reinterpret_cast<const float4*>(frow);
#pragma unroll
    for (int j = 0; j < 4; ++j) {
      int i4 = t + j * 256;
      float4 f = frow4[i4];
      v4bf o4;
      o4[0] = (__bf16)f.x; o4[1] = (__bf16)f.y; o4[2] = (__bf16)f.z; o4[3] = (__bf16)f.w;
      *(v4bf*)(s_x + 4 * i4) = o4;
    }
  }

  // ---- P0c: zero kf pad columns 64..67 (branch-free conv tail)
  if (t < 64) {
    v4bf z = {};
    *(v4bf*)(s_kf + t * 72 + 64) = z;
  }

  __syncthreads();  // bA: s_x(feat) staged

  // ---- P1: gather kf from LDS
#pragma unroll
  for (int j = 0; j < 16; ++j) {
    int i = t + j * 256;
    s_kf[(i >> 6) * 72 + (i & 63)] = s_x[idxr[j]];
  }

  // ---- P1b: tmp-GEMM  tmp[n][k'] = qin[n][k] * Wqk[k][k']  (global-only inputs)
  v4f dT[4] = {{0.f, 0.f, 0.f, 0.f}, {0.f, 0.f, 0.f, 0.f},
               {0.f, 0.f, 0.f, 0.f}, {0.f, 0.f, 0.f, 0.f}};
#pragma unroll
  for (int kt = 0; kt < 2; ++kt) {
    v8bf a = *(const v8bf*)(qin_b + (2 * w + kt) * 512 + l16 * 32 + 8 * quad);
#pragma unroll
    for (int nt = 0; nt < 4; ++nt) {
      v8bf bb = *(const v8bf*)(wqk_h + (nt * 2 + kt) * 512 + l16 * 32 + 8 * quad);
      dT[nt] = __builtin_amdgcn_mfma_f32_16x16x32_bf16(a, bb, dT[nt], 0, 0, 0);
    }
  }

  __syncthreads();  // bB: s_kf ready; feat dead

  // ---- P2a: write tmp bf16 over feat region (row-major 64x72)
#pragma unroll
  for (int nt = 0; nt < 4; ++nt)
#pragma unroll
    for (int r = 0; r < 4; ++r)
      s_x[(16 * w + 4 * quad + r) * 72 + 16 * nt + l16] = (__bf16)dT[nt][r];

  // ---- P2b: windowed conv + relu + residual -> v^T[s][n]
  {
    const int n = t & 63, p0 = (t >> 6) * 16;
    float w1[4][3], w2[4];
#pragma unroll
    for (int d = 0; d < 4; ++d) {
#pragma unroll
      for (int c = 0; c < 3; ++c) w1[d][c] = Wv1[(h * 4 + d) * 3 + c];
      w2[d] = Wv2[h * 4 + d];
    }
    v8bf xa = *(const v8bf*)(s_kf + n * 72 + p0);
    v8bf xb = *(const v8bf*)(s_kf + n * 72 + p0 + 8);
    v2bf xc = *(const v2bf*)(s_kf + n * 72 + p0 + 16);  // pad cols zeroed
    float x[18];
#pragma unroll
    for (int c = 0; c < 8; ++c) { x[c] = (float)xa[c]; x[c + 8] = (float)xb[c]; }
    x[16] = (float)xc[0]; x[17] = (float)xc[1];
#pragma unroll
    for (int pp = 0; pp < 16; ++pp) {
      float acc = x[pp];
#pragma unroll
      for (int d = 0; d < 4; ++d) {
        float v1 = fmaf(x[pp + 2], w1[d][2], fmaf(x[pp + 1], w1[d][1], x[pp] * w1[d][0]));
        acc = fmaf(fmaxf(v1, 0.f), w2[d], acc);
      }
      s_vT[(p0 + pp) * 72 + n] = (__bf16)acc;
    }
  }

  __syncthreads();  // bC: tmp, vT ready

  // ---- P3: scores[qi][n] = tmp[qi][k'] * kf[n][k']  (K=64)
  v4f ds[4] = {{0.f, 0.f, 0.f, 0.f}, {0.f, 0.f, 0.f, 0.f},
               {0.f, 0.f, 0.f, 0.f}, {0.f, 0.f, 0.f, 0.f}};
#pragma unroll
  for (int kt = 0; kt < 2; ++kt) {
    v8bf a = *(const v8bf*)(s_x + (16 * w + l16) * 72 + 32 * kt + 8 * quad);
#pragma unroll
    for (int nt = 0; nt < 4; ++nt) {
      v8bf bb = *(const v8bf*)(s_kf + (16 * nt + l16) * 72 + 32 * kt + 8 * quad);
      ds[nt] = __builtin_amdgcn_mfma_f32_16x16x32_bf16(a, bb, ds[nt], 0, 0, 0);
    }
  }

  // ---- P3b: softmax on C-layout regs (rows 16w+4quad+r, col 16nt+l16)
  v4bf attn_bf[4];  // [r] -> 4 cols (one per nt)
#pragma unroll
  for (int r = 0; r < 4; ++r) {
    float v0 = ds[0][r], v1 = ds[1][r], v2 = ds[2][r], v3 = ds[3][r];
    float mx = fmaxf(fmaxf(v0, v1), fmaxf(v2, v3));
#pragma unroll
    for (int mk = 8; mk > 0; mk >>= 1) mx = fmaxf(mx, __shfl_xor(mx, mk));
    v0 = __expf(v0 - mx); v1 = __expf(v1 - mx);
    v2 = __expf(v2 - mx); v3 = __expf(v3 - mx);
    float ssum = v0 + v1 + v2 + v3;
#pragma unroll
    for (int mk = 8; mk > 0; mk >>= 1) ssum += __shfl_xor(ssum, mk);
    const float inv = 1.0f / ssum;
    v0 *= inv; v1 *= inv; v2 *= inv; v3 *= inv;
    float* arow = attn_out + (16 * w + 4 * quad + r) * 64 + l16;
    __builtin_nontemporal_store(v0, arow);
    __builtin_nontemporal_store(v1, arow + 16);
    __builtin_nontemporal_store(v2, arow + 32);
    __builtin_nontemporal_store(v3, arow + 48);
    attn_bf[r][0] = (__bf16)v0; attn_bf[r][1] = (__bf16)v1;
    attn_bf[r][2] = (__bf16)v2; attn_bf[r][3] = (__bf16)v3;
  }

  __syncthreads();  // bD: all waves done reading kf B-frags

  // ---- P4: write attn bf16 into kf region (wave-own rows; A-layout row-major)
#pragma unroll
  for (int r = 0; r < 4; ++r)
#pragma unroll
    for (int nt = 0; nt < 4; ++nt)
      s_kf[(16 * w + 4 * quad + r) * 72 + 16 * nt + l16] = attn_bf[r][nt];

  // ---- P5: o[qi][s] = attn[qi][n] * vT[s][n]
  v4f dO[4] = {{0.f, 0.f, 0.f, 0.f}, {0.f, 0.f, 0.f, 0.f},
               {0.f, 0.f, 0.f, 0.f}, {0.f, 0.f, 0.f, 0.f}};
#pragma unroll
  for (int kt = 0; kt < 2; ++kt) {
    v8bf a = *(const v8bf*)(s_kf + (16 * w + l16) * 72 + 32 * kt + 8 * quad);
#pragma unroll
    for (int st = 0; st < 4; ++st) {
      v8bf bb = *(const v8bf*)(s_vT + (16 * st + l16) * 72 + 32 * kt + 8 * quad);
      dO[st] = __builtin_amdgcn_mfma_f32_16x16x32_bf16(a, bb, dO[st], 0, 0, 0);
    }
  }

  // ---- P6: store o to ws in A-fragment tile order
  __bf16* obase = o_ws + ((size_t)(b * 4 + w) * 16 + h * 2) * 512;
#pragma unroll
  for (int st = 0; st < 4; ++st)
#pragma unroll
    for (int r = 0; r < 4; ++r)
      obase[(st >> 1) * 512 + (4 * quad + r) * 32 + (st & 1) * 16 + l16] = (__bf16)dO[st][r];
}

// ---------------- K3: fc GEMM, fully coalesced tile loads ----------------
__global__ __launch_bounds__(256, 4) void k3_fc(
    const __bf16* __restrict__ o_ws, const __bf16* __restrict__ wfc,
    float* __restrict__ out) {
  const int t = threadIdx.x, w = t >> 6, lid = t & 63;
  const int quad = lid >> 4, l16 = lid & 15;
  const size_t row0 = (size_t)blockIdx.x * 64 + 16 * w;
  const __bf16* abase = o_ws + (size_t)(blockIdx.x * 4 + w) * 16 * 512;
  v4f d[4] = {{0.f, 0.f, 0.f, 0.f}, {0.f, 0.f, 0.f, 0.f},
              {0.f, 0.f, 0.f, 0.f}, {0.f, 0.f, 0.f, 0.f}};
#pragma unroll 4
  for (int kt = 0; kt < 16; ++kt) {
    v8bf a = *(const v8bf*)(abase + kt * 512 + l16 * 32 + 8 * quad);
#pragma unroll
    for (int nt = 0; nt < 4; ++nt) {
      v8bf bb = *(const v8bf*)(wfc + (size_t)(nt * 16 + kt) * 512 + l16 * 32 + 8 * quad);
      d[nt] = __builtin_amdgcn_mfma_f32_16x16x32_bf16(a, bb, d[nt], 0, 0, 0);
    }
  }
#pragma unroll
  for (int nt = 0; nt < 4; ++nt)
#pragma unroll
    for (int r = 0; r < 4; ++r)
      out[(row0 + 4 * quad + r) * 64 + 16 * nt + l16] = d[nt][r];
}

}  // namespace

extern "C" void kernel_launch(void* const* d_in, const int* in_sizes, int n_in,
                              void* d_out, int out_size, void* d_ws, size_t ws_size,
                              hipStream_t stream) {
  (void)in_sizes; (void)n_in; (void)out_size; (void)ws_size;
  const float* features = (const float*)d_in[0];
  const int*   sidx     = (const int*)d_in[1];
  const float* gamma    = (const float*)d_in[2];
  const float* beta     = (const float*)d_in[3];
  const float* Wq       = (const float*)d_in[4];
  const float* Wk       = (const float*)d_in[5];
  const float* Wv1      = (const float*)d_in[6];
  const float* Wv2      = (const float*)d_in[7];
  const float* Wfc      = (const float*)d_in[8];
  float* out = (float*)d_out;

  char* ws = (char*)d_ws;
  __bf16* ws_qin = (__bf16*)(ws + WS_QIN);
  __bf16* ws_o   = (__bf16*)(ws + WS_O);
  __bf16* ws_wfc = (__bf16*)(ws + WS_WFC);
  __bf16* ws_wqk = (__bf16*)(ws + WS_WQK);

  hipLaunchKernelGGL(k0_wfc, dim3(128), dim3(256), 0, stream, Wfc, ws_wfc);
  hipLaunchKernelGGL(k0b_wqk, dim3(kH), dim3(256), 0, stream, Wq, Wk, ws_wqk);
  hipLaunchKernelGGL(k1_ln, dim3(kB), dim3(256), 0, stream,
                     features, gamma, beta, ws_qin);
  hipLaunchKernelGGL(k2_attn, dim3(kB, kH), dim3(256), 0, stream,
                     features, sidx, ws_qin, ws_wqk, Wv1, Wv2, ws_o, out);
  hipLaunchKernelGGL(k3_fc, dim3(kB), dim3(256), 0, stream,
                     ws_o, ws_wfc, out);
}